// Round 2
// baseline (19739.151 us; speedup 1.0000x reference)
//
#include <hip/hip_runtime.h>
#include <hip/hip_bf16.h>
#include <stdint.h>

typedef __attribute__((ext_vector_type(8))) short s16x8;   // 8 bf16 (4 VGPRs)
typedef __attribute__((ext_vector_type(4))) float f32x4;
typedef unsigned short u16;
typedef unsigned int u32;
typedef unsigned long long u64;

#define FEAT 2048
#define HID  512
#define GATES 2048   // 4*HID
#define NB   16
#define NT   2048
#define NOUT 22
#define MROWS (NB*NT)   // 32768

// ---- workspace layout (bytes) ----
#define WS_FLAG 0L
#define WS_BIAS 4096L                      // [2][2048] f32 = 16384
#define WS_WHB  (WS_BIAS + 16384L)         // [2][2048][512] u16 = 4 MiB
#define WS_WB   (WS_WHB + 4194304L)        // [2][2048][2048] u16 = 16 MiB
#define WS_XB   (WS_WB + 16777216L)        // x as bf16 = 128 MiB
#define WS_XG   (WS_XB + 134217728L)       // [2][32768][2048] u16 = 256 MiB
#define WS_HB   (WS_XG + 268435456L)       // [2][2049][16][512] u16 = 67,141,632 B
#define HB_BYTES 67141632L
#define HB_LSTM_U64 (2049L*2048L)          // u64 per lstm
#define HB_SLAB_U64 2048L                  // u64 per (lstm,t) slab

__device__ inline float b2f(u16 u){ u32 x = ((u32)u) << 16; return __builtin_bit_cast(float, x); }
__device__ inline u16 f2b(float f){
  u32 u = __builtin_bit_cast(u32, f);
  u32 r = (u + 0x7FFFu + ((u >> 16) & 1u)) >> 16;   // RNE
  return (u16)r;
}
__device__ inline float sigm(float x){ return __builtin_amdgcn_rcpf(1.f + __expf(-x)); }
__device__ inline float tanh_(float x){ return 1.f - 2.f*__builtin_amdgcn_rcpf(1.f + __expf(2.f*x)); }

// ---------------- dtype detector ----------------
__global__ void detect_dtype(const u32* __restrict__ x, int* __restrict__ flag){
  __shared__ int cs;
  if (threadIdx.x == 0) cs = 0;
  __syncthreads();
  int c = 0;
  for (int i = 0; i < 16; i++){
    u32 w = x[threadIdx.x*16 + i];
    u32 e = (w >> 7) & 0xFFu;
    if ((e >= 110u && e <= 134u) || ((w & 0xFFFFu) == 0u)) c++;
  }
  atomicAdd(&cs, c);
  __syncthreads();
  if (threadIdx.x == 0) *flag = (cs > 2048) ? 1 : 0;
}

// ---------------- fp32|bf16 -> bf16 conversion/copy ----------------
__global__ void cvt_bf16(const void* __restrict__ src, u16* __restrict__ dst,
                         long n8, const int* __restrict__ flag){
  const int isb = *flag;
  long stride = (long)gridDim.x * blockDim.x;
  for (long i = (long)blockIdx.x*blockDim.x + threadIdx.x; i < n8; i += stride){
    if (isb){
      ((int4*)dst)[i] = ((const int4*)src)[i];
    } else {
      const float4* s = (const float4*)src + 2*i;
      float4 a = s[0], b = s[1];
      s16x8 o;
      o[0]=(short)f2b(a.x); o[1]=(short)f2b(a.y); o[2]=(short)f2b(a.z); o[3]=(short)f2b(a.w);
      o[4]=(short)f2b(b.x); o[5]=(short)f2b(b.y); o[6]=(short)f2b(b.z); o[7]=(short)f2b(b.w);
      *(s16x8*)(dst + i*8) = o;
    }
  }
}

// ---------------- bias combine ----------------
__global__ void bias_sum(const void* bi0, const void* bh0, const void* bi1, const void* bh1,
                         float* __restrict__ out, const int* __restrict__ flag){
  const int isb = *flag;
  int i = blockIdx.x*256 + threadIdx.x;     // 0..4095
  int lstm = i >> 11, idx = i & 2047;
  const void* bi = lstm ? bi1 : bi0;
  const void* bh = lstm ? bh1 : bh0;
  float a = isb ? b2f(((const u16*)bi)[idx]) : ((const float*)bi)[idx];
  float b = isb ? b2f(((const u16*)bh)[idx]) : ((const float*)bh)[idx];
  out[i] = a + b;
}

// ---------------- xg GEMM (unchanged from round 1, verified) ----------------
__global__ __launch_bounds__(256,2) void gemm_xg(const u16* __restrict__ xb,
    const u16* __restrict__ wb, const float* __restrict__ bias, u16* __restrict__ xg){
  __shared__ u16 As[2][128*64];
  __shared__ u16 Bs[2][128*64];
  const int lstm = blockIdx.z;
  const int n0 = blockIdx.x * 128;
  const int m0 = blockIdx.y * 128;
  const int tid = threadIdx.x;
  const int lane = tid & 63;
  const int wid = tid >> 6;
  const int wr = wid >> 1, wc = wid & 1;
  const u16* Bw = wb + (size_t)lstm * GATES * FEAT;

  f32x4 acc[4][4] = {};

  auto stage = [&](int buf, int kt){
    const int k0 = kt*64;
#pragma unroll
    for (int i = 0; i < 4; i++){
      int cc = tid + 256*i;
      int row = cc >> 3;
      int slot = cc & 7;
      int slotp = slot ^ (row & 7);
      const u16* ga = xb + (size_t)(m0+row)*FEAT + k0 + slotp*8;
      const u16* gb = Bw + (size_t)(n0+row)*FEAT + k0 + slotp*8;
      __builtin_amdgcn_global_load_lds((const __attribute__((address_space(1))) void*)ga,
          (__attribute__((address_space(3))) void*)&As[buf][cc*8], 16, 0, 0);
      __builtin_amdgcn_global_load_lds((const __attribute__((address_space(1))) void*)gb,
          (__attribute__((address_space(3))) void*)&Bs[buf][cc*8], 16, 0, 0);
    }
  };

  stage(0, 0);
  __syncthreads();
  for (int kt = 0; kt < 32; kt++){
    int buf = kt & 1;
    if (kt < 31) stage(buf^1, kt+1);
    const char* Ab = (const char*)&As[buf][0];
    const char* Bb = (const char*)&Bs[buf][0];
#pragma unroll
    for (int ks = 0; ks < 2; ks++){
      s16x8 af[4], bf[4];
#pragma unroll
      for (int mi = 0; mi < 4; mi++){
        int row = wr*64 + mi*16 + (lane & 15);
        int off = row*128 + ((ks*64 + ((lane>>4)*16)) ^ ((row & 7) << 4));
        af[mi] = *(const s16x8*)(Ab + off);
      }
#pragma unroll
      for (int ni = 0; ni < 4; ni++){
        int row = wc*64 + ni*16 + (lane & 15);
        int off = row*128 + ((ks*64 + ((lane>>4)*16)) ^ ((row & 7) << 4));
        bf[ni] = *(const s16x8*)(Bb + off);
      }
#pragma unroll
      for (int mi = 0; mi < 4; mi++)
#pragma unroll
        for (int ni = 0; ni < 4; ni++)
          acc[mi][ni] = __builtin_amdgcn_mfma_f32_16x16x32_bf16(af[mi], bf[ni], acc[mi][ni], 0, 0, 0);
    }
    __syncthreads();
  }

  u16* xgl = xg + (size_t)lstm * MROWS * GATES;
#pragma unroll
  for (int mi = 0; mi < 4; mi++){
#pragma unroll
    for (int ni = 0; ni < 4; ni++){
      int gcol = n0 + wc*64 + ni*16 + (lane & 15);
      float bv = bias[lstm*GATES + gcol];
#pragma unroll
      for (int r = 0; r < 4; r++){
        int grow = m0 + wr*64 + mi*16 + ((lane>>4)<<2) + r;
        xgl[(size_t)grow*GATES + gcol] = f2b(acc[mi][ni][r] + bv);
      }
    }
  }
}

// ---------------- persistent recurrent kernel (fence-free sentinel sync) ----
// 32 WGs: [lstm(2)] x [w(16 hid-slices of 32)]. 256 threads = 4 waves.
// Wave wv owns 32 gate-rows: j = q*512 + w*32 + wv*8 + m*4 + p  (m=0,1 col groups).
// W_hh pinned in VGPRs (128/lane). h(t) exchange: time-indexed hb[lstm][t][b][hid]
// via relaxed agent-scope u64 atomics (IC-coherent, NO fences). Each u64
// self-validates: sentinel 0xFFFF per u16 (= -NaN bf16, never produced).
// Wave0 polls h(t) into LDS; 2 light barriers/step; zero cache-maintenance ops.
__global__ __launch_bounds__(256,1) void lstm_rec(const u16* __restrict__ whb,
    const u16* __restrict__ xg, u64* __restrict__ hb64){
  __shared__ u16 Hl[16*512];                 // 16 KiB, row b stride 1 KiB, XOR-swizzled
  const int blk = blockIdx.x;
  const int lstm = blk >> 4;
  const int w = blk & 15;
  const int tid = threadIdx.x;
  const int lane = tid & 63;
  const int wv = tid >> 6;                   // 0..3
  const int n = lane & 15;
  const int q = n & 3;                       // gate: i,f,g,o
  const int p = n >> 2;
  const int g = lane >> 4;                   // k-chunk group
  const int khb = g * 16;                    // byte offset of 8-elem k-chunk
  const int b0 = g * 4;

  // ---- W_hh fragments -> pinned VGPRs: wf[m][kk] = W[j(m)][kk*32+g*8 .. +8]
  s16x8 wf[2][16];
#pragma unroll
  for (int m = 0; m < 2; m++){
    const int jm = q*512 + w*32 + wv*8 + m*4 + p;
    const u16* wrow = whb + ((size_t)lstm*GATES + jm)*HID;
#pragma unroll
    for (int kk = 0; kk < 16; kk++){
      wf[m][kk] = *(const s16x8*)(wrow + kk*32 + g*8);
      asm volatile("" : "+v"(*reinterpret_cast<f32x4*>(&wf[m][kk])));   // pin: no remat
    }
  }

  const char* hbase = (const char*)Hl + n*1024;
  const int xmh = (n & 7) << 4;
  u64* myslab = hb64 + (size_t)lstm * HB_LSTM_U64;

  // xg pointers: row r -> batch b0+r, cols j0=q*512+w*32+wv*8+p (+4 for m=1)
  const u16* xp[4];
  u16 xv[2][4], xn[2][4];
#pragma unroll
  for (int r = 0; r < 4; r++){
    xp[r] = xg + (size_t)lstm*MROWS*GATES + (size_t)(b0+r)*NT*GATES
               + (q*512 + w*32 + wv*8 + p);
    xv[0][r] = xp[r][0];
    xv[1][r] = xp[r][4];
  }
  float c[2][4] = {};
  int wd = 0;                                // global poll watchdog

  for (int t = 0; t < NT; t++){
    // ---- wave0: poll h(t) (self-validating) and stage into LDS ----
    if (wv == 0){
      const u64* src = myslab + (size_t)t*HB_SLAB_U64 + lane*32;
      u64 val[32];
      u32 pend = 0xFFFFFFFFu;
      do {
        u32 np = 0;
#pragma unroll
        for (int s = 0; s < 32; s++){
          if (pend & (1u << s)){
            u64 v = __hip_atomic_load(src + s, __ATOMIC_RELAXED, __HIP_MEMORY_SCOPE_AGENT);
            if ((((~v) - 0x0001000100010001ULL) & v & 0x8000800080008000ULL))
              np |= (1u << s);
            else val[s] = v;
          }
        }
        pend = np;
        if (pend) __builtin_amdgcn_s_sleep(1);
      } while (pend && ++wd < 200000);
      // swizzled LDS write: lane covers batch b=lane>>2, u64s rembase..+31
      const int b = lane >> 2;
      char* hdst = (char*)Hl + b*1024;
      const int xm = (b & 7) << 4;
      const int rembase = (lane & 3) * 32;
#pragma unroll
      for (int s = 0; s < 32; s++)
        *(u64*)(hdst + (((rembase + s)*8) ^ xm)) = val[s];
    }
    __syncthreads();                          // B1: h(t) staged

    // ---- all waves: LDS -> A fragments ----
    s16x8 hf[16];
#pragma unroll
    for (int kk = 0; kk < 16; kk++)
      hf[kk] = *(const s16x8*)(hbase + ((kk*64 + khb) ^ xmh));
    __syncthreads();                          // B2: Hl consumable next iter

    // ---- MFMA: 2 col-groups x 16 k-steps ----
    f32x4 acc[2] = {};
#pragma unroll
    for (int kk = 0; kk < 16; kk++){
      acc[0] = __builtin_amdgcn_mfma_f32_16x16x32_bf16(hf[kk], wf[0][kk], acc[0], 0, 0, 0);
      acc[1] = __builtin_amdgcn_mfma_f32_16x16x32_bf16(hf[kk], wf[1][kk], acc[1], 0, 0, 0);
    }

    // ---- gates + cell update ----
    const int base = lane & 60;               // 4-lane gate group
    u16 hob[2][4];
#pragma unroll
    for (int m = 0; m < 2; m++){
#pragma unroll
      for (int r = 0; r < 4; r++){
        float gg = acc[m][r] + b2f(xv[m][r]);
        float iv = __shfl(gg, base+0, 64);
        float fv = __shfl(gg, base+1, 64);
        float gv = __shfl(gg, base+2, 64);
        float ov = __shfl(gg, base+3, 64);
        float cn = sigm(fv)*c[m][r] + sigm(iv)*tanh_(gv);
        c[m][r] = cn;
        hob[m][r] = f2b(sigm(ov)*tanh_(cn));
      }
    }

    // ---- prefetch next xg ----
    const int tn = (t < NT-1) ? (t+1) : t;
#pragma unroll
    for (int r = 0; r < 4; r++){
      xn[0][r] = xp[r][(size_t)tn * GATES];
      xn[1][r] = xp[r][(size_t)tn * GATES + 4];
    }

    // ---- pack h(t+1) u64s via shuffles, publish with relaxed agent atomics ----
    u64* dst = myslab + (size_t)(t+1)*HB_SLAB_U64;
    const int gbase = lane & 48;
#pragma unroll
    for (int m = 0; m < 2; m++){
#pragma unroll
      for (int r = 0; r < 4; r++){
        int h0 = __shfl((int)hob[m][r], gbase+0,  64) & 0xFFFF;
        int h1 = __shfl((int)hob[m][r], gbase+4,  64) & 0xFFFF;
        int h2 = __shfl((int)hob[m][r], gbase+8,  64) & 0xFFFF;
        int h3 = __shfl((int)hob[m][r], gbase+12, 64) & 0xFFFF;
        u64 v = (u64)(u32)(h0 | (h1 << 16)) | ((u64)(u32)(h2 | (h3 << 16)) << 32);
        if (q == 0 && p == r){
          int B = b0 + r;
          __hip_atomic_store(dst + B*128 + w*8 + wv*2 + m, v,
                             __ATOMIC_RELAXED, __HIP_MEMORY_SCOPE_AGENT);
        }
      }
    }
#pragma unroll
    for (int r = 0; r < 4; r++){ xv[0][r] = xn[0][r]; xv[1][r] = xn[1][r]; }
  }
}

// ---------------- linear heads: out = h @ fc_w^T + fc_b (reads hb[t+1]) ------
__global__ __launch_bounds__(256,4) void head_fc(const u16* __restrict__ hb,
    const void* fcw0, const void* fcb0, const void* fcw1, const void* fcb1,
    void* __restrict__ dout, const int* __restrict__ flag){
  const int isb = *flag;
  const int lane = threadIdx.x & 63;
  const int wv = threadIdx.x >> 6;
  int row = blockIdx.x*4 + wv;                 // lstm*32768 + b*2048 + t
  const int lstm = row >> 15;
  const int rem = row & 32767;
  const int b = rem >> 11;
  const int t = rem & 2047;
  const u16* hrow = hb + (((size_t)lstm*2049 + (t+1))*16 + b)*512;
  float hv[8];
  {
    s16x8 h8 = *(const s16x8*)(hrow + lane*8);
#pragma unroll
    for (int e = 0; e < 8; e++) hv[e] = b2f((u16)h8[e]);
  }
  const void* fcw = lstm ? fcw1 : fcw0;
  const void* fcb = lstm ? fcb1 : fcb0;
  float bval = 0.f;
  if (lane < NOUT) bval = isb ? b2f(((const u16*)fcb)[lane]) : ((const float*)fcb)[lane];
  float res = 0.f;
  for (int o = 0; o < NOUT; o++){
    float pa = 0.f;
    if (isb){
      s16x8 w8 = *(const s16x8*)((const u16*)fcw + (size_t)o*HID + lane*8);
#pragma unroll
      for (int e = 0; e < 8; e++) pa += hv[e] * b2f((u16)w8[e]);
    } else {
      const float* wr = (const float*)fcw + (size_t)o*HID + lane*8;
#pragma unroll
      for (int e = 0; e < 8; e++) pa += hv[e] * wr[e];
    }
#pragma unroll
    for (int d = 1; d < 64; d <<= 1) pa += __shfl_xor(pa, d, 64);
    if (lane == o) res = pa + bval;
  }
  size_t off = (size_t)lstm*(MROWS*NOUT) + (size_t)rem*NOUT;
  if (lane < NOUT){
    if (isb) ((u16*)dout)[off + lane] = f2b(res);
    else     ((float*)dout)[off + lane] = res;
  }
}

extern "C" void kernel_launch(void* const* d_in, const int* in_sizes, int n_in,
                              void* d_out, int out_size, void* d_ws, size_t ws_size,
                              hipStream_t stream){
  char* ws = (char*)d_ws;
  int*   flag = (int*)(ws + WS_FLAG);
  float* bias = (float*)(ws + WS_BIAS);
  u16*   whb  = (u16*)(ws + WS_WHB);
  u16*   wb   = (u16*)(ws + WS_WB);
  u16*   xb   = (u16*)(ws + WS_XB);
  u16*   xg   = (u16*)(ws + WS_XG);
  u16*   hb   = (u16*)(ws + WS_HB);

  hipMemsetAsync(ws + WS_FLAG, 0, 4096, stream);
  // sentinel-fill h history, then zero the t=0 slabs (h(0)=0)
  hipMemsetAsync(ws + WS_HB, 0xFF, HB_BYTES, stream);
  hipMemsetAsync(ws + WS_HB, 0, 16384, stream);
  hipMemsetAsync(ws + WS_HB + 2049L*16*512*2, 0, 16384, stream);

  detect_dtype<<<1, 256, 0, stream>>>((const u32*)d_in[0], flag);

  cvt_bf16<<<2048, 256, 0, stream>>>(d_in[0], xb,             67108864L/8, flag); // x
  cvt_bf16<<<2048, 256, 0, stream>>>(d_in[1], wb,              4194304L/8, flag); // w_ih
  cvt_bf16<<<2048, 256, 0, stream>>>(d_in[5], wb + 4194304L,   4194304L/8, flag); // w_ih_ed
  cvt_bf16<<< 512, 256, 0, stream>>>(d_in[2], whb,             1048576L/8, flag); // w_hh
  cvt_bf16<<< 512, 256, 0, stream>>>(d_in[6], whb + 1048576L,  1048576L/8, flag); // w_hh_ed
  bias_sum<<<16, 256, 0, stream>>>(d_in[3], d_in[4], d_in[7], d_in[8], bias, flag);

  gemm_xg<<<dim3(16, 256, 2), 256, 0, stream>>>(xb, wb, bias, xg);
  lstm_rec<<<32, 256, 0, stream>>>(whb, xg, (u64*)hb);
  head_fc<<<16384, 256, 0, stream>>>(hb, d_in[9], d_in[10], d_in[11], d_in[12], d_out, flag);
}